// Round 14
// baseline (76.901 us; speedup 1.0000x reference)
//
#include <hip/hip_runtime.h>

typedef __attribute__((ext_vector_type(4))) float v4f;
typedef __attribute__((ext_vector_type(8))) short short8;
typedef unsigned short u16;
typedef unsigned int u32;
typedef __attribute__((ext_vector_type(2))) unsigned int u32x2;
typedef __attribute__((ext_vector_type(8))) unsigned short u16x8;

#define CDIM 256
#define NB 8
#define NN 4096
#define MM 4096
#define PANEL 8192  // u16 per 32-row panel (256 c x 32 m)

static __device__ __forceinline__ u16 f2bf(float f) {
  unsigned u = __float_as_uint(f);
  u = (u + 0x7fffu + ((u >> 16) & 1u)) >> 16;  // RNE
  return (u16)u;
}
static __device__ __forceinline__ float bf2f(u16 h) {
  return __uint_as_float(((unsigned)h) << 16);
}
static __device__ __forceinline__ u32 pack2(float a, float b) {
  return (u32)f2bf(a) | ((u32)f2bf(b) << 16);
}

// swizzled index into a [256 c][32 m] u16 panel (proven R9-R12)
static __device__ __forceinline__ int sidx32(int c, int m) {
  return (c * 32 + m) ^ (((c >> 1) & 7) << 3);
}

// 4x4 bf16 transpose among lanes {l, l^16, l^32, l^48} (proven R7-R12).
static __device__ __forceinline__ u32x2 xpose4(u32 A, u32 B, int hi) {
  u32 tA = (u32)__shfl_xor((int)A, 32);
  u32 tB = (u32)__shfl_xor((int)B, 32);
  u32 U = (hi < 2) ? A : tB;
  u32 V = (hi < 2) ? tA : B;
  u32 tU = (u32)__shfl_xor((int)U, 16);
  u32 tV = (u32)__shfl_xor((int)V, 16);
  u32 Up, Vp;
  if ((hi & 1) == 0) {
    Up = (U & 0xffffu) | (tU << 16);
    Vp = (V & 0xffffu) | (tV << 16);
  } else {
    Up = (tU >> 16) | (U & 0xffff0000u);
    Vp = (tV >> 16) | (V & 0xffff0000u);
  }
  return (u32x2){Up, Vp};
}

// ---------------- K0: streaming convert+transpose (NO barriers, red-style TLP) ----------------
// 1024 blocks x 512 thr; block = one 32-row panel; wave w owns rows w*4..w*4+3.
// Writes bf16 k-hat^T and v^T panels, sidx32-swizzled IN GLOBAL (pre-swizzle pattern).
__global__ __launch_bounds__(512) void conv_kernel(const float* __restrict__ key,
                                                   const float* __restrict__ value,
                                                   u16* __restrict__ ktp,
                                                   u16* __restrict__ vtp) {
  int t = threadIdx.x;
  int w = t >> 6, lane = t & 63, lo = lane & 15, hi = lane >> 4;
  int m0 = w * 4;
  size_t grow = (size_t)blockIdx.x * 32 + m0 + hi;
  const float* kr = key + grow * CDIM + lo * 4;
  const float* vr = value + grow * CDIM + lo * 4;
  v4f kq[4], vq[4];
  #pragma unroll
  for (int qt = 0; qt < 4; ++qt) {
    kq[qt] = *(const v4f*)(kr + qt * 64);
    vq[qt] = *(const v4f*)(vr + qt * 64);
  }
  float ss = 0.f;
  #pragma unroll
  for (int qt = 0; qt < 4; ++qt)
    ss += kq[qt][0]*kq[qt][0] + kq[qt][1]*kq[qt][1] + kq[qt][2]*kq[qt][2] + kq[qt][3]*kq[qt][3];
  #pragma unroll
  for (int m = 1; m < 16; m <<= 1) ss += __shfl_xor(ss, m);  // row spans 16 lanes (lo)
  float sc_ = 1.0f / fmaxf(sqrtf(ss), 1e-12f);
  u16* kp = ktp + (size_t)blockIdx.x * PANEL;
  u16* vp = vtp + (size_t)blockIdx.x * PANEL;
  #pragma unroll
  for (int qt = 0; qt < 4; ++qt) {
    int c = qt * 64 + lo * 4 + hi;
    int idx = sidx32(c, m0);
    u32x2 ko = xpose4(pack2(kq[qt][0] * sc_, kq[qt][1] * sc_),
                      pack2(kq[qt][2] * sc_, kq[qt][3] * sc_), hi);
    *(u32x2*)&kp[idx] = ko;
    u32x2 vo = xpose4(pack2(vq[qt][0], vq[qt][1]),
                      pack2(vq[qt][2], vq[qt][3]), hi);
    *(u32x2*)&vp[idx] = vo;
  }
}

// ---------------- K1: partial = v^T @ k-hat, split-K, from pre-transposed panels ----------------
// Staging is a LINEAR 16-u16/thread copy (swizzle pre-baked): 2 loads + 2 ds_writes per
// lane per operand per subtile. No norm/shfl/transpose in the loop.
__global__ __launch_bounds__(512) void gemm_kernel(const u16* __restrict__ ktp,
                                                   const u16* __restrict__ vtp,
                                                   u16* __restrict__ partial, int KC) {
  __shared__ __align__(16) u16 KL[2][PANEL];  // 16 KB each
  __shared__ __align__(16) u16 VL[2][PANEL];
  int t = threadIdx.x;
  int b = blockIdx.y, s = blockIdx.x;
  int w = t >> 6, lane = t & 63, lo = lane & 15, hi = lane >> 4;
  size_t p0 = ((size_t)b * MM + (size_t)s * KC) >> 5;  // first panel index

  v4f acc[2][16];
  #pragma unroll
  for (int i = 0; i < 2; i++)
    #pragma unroll
    for (int d = 0; d < 16; d++) acc[i][d] = (v4f){0.f, 0.f, 0.f, 0.f};

  int soff = t * 16;  // 512 thr x 16 u16 = 8192 = PANEL (full coverage)

  auto MF = [&](const u16* KB, const u16* VB) {
    int acol = hi * 8;
    int r0 = w * 32 + lo, r1 = w * 32 + 16 + lo;
    short8 a0 = *(const short8*)&KB[(r0 * 32 + acol) ^ (((r0 >> 1) & 7) << 3)];
    short8 a1 = *(const short8*)&KB[(r1 * 32 + acol) ^ (((r1 >> 1) & 7) << 3)];
    #pragma unroll
    for (int dt = 0; dt < 16; ++dt) {
      int drow = dt * 16 + lo;
      short8 bb = *(const short8*)&VB[(drow * 32 + acol) ^ (((drow >> 1) & 7) << 3)];
      acc[0][dt] = __builtin_amdgcn_mfma_f32_16x16x32_bf16(bb, a0, acc[0][dt], 0, 0, 0);
      acc[1][dt] = __builtin_amdgcn_mfma_f32_16x16x32_bf16(bb, a1, acc[1][dt], 0, 0, 0);
    }
  };

  int nsc = KC >> 5;
  // prologue: stage panel 0 (16 u16 per thread = 2 x u16x8)
  {
    u16x8 k0 = *(const u16x8*)&ktp[p0 * PANEL + soff];
    u16x8 k1 = *(const u16x8*)&ktp[p0 * PANEL + soff + 8];
    u16x8 v0 = *(const u16x8*)&vtp[p0 * PANEL + soff];
    u16x8 v1 = *(const u16x8*)&vtp[p0 * PANEL + soff + 8];
    *(u16x8*)&KL[0][soff] = k0;
    *(u16x8*)&KL[0][soff + 8] = k1;
    *(u16x8*)&VL[0][soff] = v0;
    *(u16x8*)&VL[0][soff + 8] = v1;
  }
  __syncthreads();
  for (int sc = 0; sc < nsc; ++sc) {
    u16x8 k0N, k1N, v0N, v1N;
    if (sc + 1 < nsc) {  // issue next panel's loads; they fly during MF
      size_t pb = (p0 + sc + 1) * PANEL + soff;
      k0N = *(const u16x8*)&ktp[pb];
      k1N = *(const u16x8*)&ktp[pb + 8];
      v0N = *(const u16x8*)&vtp[pb];
      v1N = *(const u16x8*)&vtp[pb + 8];
    }
    MF(KL[sc & 1], VL[sc & 1]);
    if (sc + 1 < nsc) {
      int nb = (sc + 1) & 1;
      *(u16x8*)&KL[nb][soff] = k0N;
      *(u16x8*)&KL[nb][soff + 8] = k1N;
      *(u16x8*)&VL[nb][soff] = v0N;
      *(u16x8*)&VL[nb][soff + 8] = v1N;
    }
    __syncthreads();
  }

  // epilogue: bf16 partial [s][b][256 d][256 c] (proven form)
  size_t base = ((size_t)(s * NB + b)) << 16;
  #pragma unroll
  for (int i = 0; i < 2; i++) {
    int cc = w * 32 + i * 16 + lo;
    #pragma unroll
    for (int dt = 0; dt < 16; ++dt) {
      int dd = dt * 16 + hi * 4;
      #pragma unroll
      for (int r = 0; r < 4; r++)
        partial[base + (size_t)(dd + r) * 256 + cc] = f2bf(acc[i][dt][r]);
    }
  }
}

// ---------------- K2: elementwise reduce partials, scale 1/N, write kvT[d][c] bf16 ----------------
__global__ __launch_bounds__(256) void red_kernel(const u16* __restrict__ partial,
                                                  u16* __restrict__ kvT, int splits) {
  int j = blockIdx.x * 256 + threadIdx.x;   // 0..65535
  int b = j >> 13;
  int e0 = (j & 8191) * 8;
  size_t off = ((size_t)b << 16) + e0;
  const float inv = 1.0f / 4096.0f;
  float sum[8] = {0.f, 0.f, 0.f, 0.f, 0.f, 0.f, 0.f, 0.f};
  for (int s = 0; s < splits; ++s) {
    u16x8 p = *(const u16x8*)&partial[(((size_t)s * NB) << 16) + off];
    #pragma unroll
    for (int x = 0; x < 8; ++x) sum[x] += bf2f(p[x]);
  }
  u16x8 o;
  #pragma unroll
  for (int x = 0; x < 8; ++x) o[x] = f2bf(sum[x] * inv);
  *(u16x8*)&kvT[off] = o;
}

// ---------------- K3: out = normalize(q) @ kv (unchanged, proven) ----------------
__global__ __launch_bounds__(512) void ctx_kernel(const float* __restrict__ query,
                                                  const u16* __restrict__ kvT,
                                                  float* __restrict__ out) {
  __shared__ __align__(16) u16 qn[2][16 * 256];
  int t = threadIdx.x;
  int b = blockIdx.y;
  int tile0 = blockIdx.x * 4;
  int w = t >> 6, lane = t & 63, lo = lane & 15, hi = lane >> 4;
  int row = t >> 5, l32 = t & 31;
  const float* qbase = query + (size_t)b * NN * CDIM + (size_t)row * CDIM + l32 * 8;

  const float* qr0 = qbase + (size_t)(tile0 * 16) * CDIM;
  v4f x0 = *(const v4f*)qr0;
  v4f x1 = *(const v4f*)(qr0 + 4);

  const u16* kvb = kvT + ((size_t)b << 16);
  short8 Bf[2][8];
  #pragma unroll
  for (int i = 0; i < 2; i++) {
    int dr = (2 * w + i) * 16 + lo;
    #pragma unroll
    for (int kc = 0; kc < 8; kc++)
      Bf[i][kc] = *(const short8*)&kvb[(size_t)dr * 256 + kc * 32 + 8 * hi];
  }

  {
    float ss = x0[0]*x0[0] + x0[1]*x0[1] + x0[2]*x0[2] + x0[3]*x0[3]
             + x1[0]*x1[0] + x1[1]*x1[1] + x1[2]*x1[2] + x1[3]*x1[3];
    #pragma unroll
    for (int m = 1; m < 32; m <<= 1) ss += __shfl_xor(ss, m);
    float sc = 1.0f / fmaxf(sqrtf(ss), 1e-12f);
    u16x8 qb;
    qb[0] = f2bf(x0[0] * sc); qb[1] = f2bf(x0[1] * sc);
    qb[2] = f2bf(x0[2] * sc); qb[3] = f2bf(x0[3] * sc);
    qb[4] = f2bf(x1[0] * sc); qb[5] = f2bf(x1[1] * sc);
    qb[6] = f2bf(x1[2] * sc); qb[7] = f2bf(x1[3] * sc);
    *(u16x8*)&qn[0][(row * 256 + l32 * 8) ^ ((row & 7) << 3)] = qb;
  }

  int cur = 0;
  #pragma unroll
  for (int nt = 0; nt < 4; ++nt) {
    v4f p0, p1;
    if (nt < 3) {
      const float* qr = qbase + (size_t)((tile0 + nt + 1) * 16) * CDIM;
      p0 = *(const v4f*)qr;
      p1 = *(const v4f*)(qr + 4);
    }
    __syncthreads();
    short8 Af[8];
    #pragma unroll
    for (int kc = 0; kc < 8; kc++)
      Af[kc] = *(const short8*)&qn[cur][(lo * 256 + kc * 32 + 8 * hi) ^ ((lo & 7) << 3)];
    v4f acc0 = (v4f){0.f, 0.f, 0.f, 0.f};
    v4f acc1 = (v4f){0.f, 0.f, 0.f, 0.f};
    #pragma unroll
    for (int kc = 0; kc < 8; kc++) {
      acc0 = __builtin_amdgcn_mfma_f32_16x16x32_bf16(Af[kc], Bf[0][kc], acc0, 0, 0, 0);
      acc1 = __builtin_amdgcn_mfma_f32_16x16x32_bf16(Af[kc], Bf[1][kc], acc1, 0, 0, 0);
    }
    int n0 = (tile0 + nt) * 16;
    #pragma unroll
    for (int r = 0; r < 4; r++) {
      size_t ro = (size_t)(b * NN + n0 + 4 * hi + r) * CDIM;
      out[ro + (2 * w) * 16 + lo] = acc0[r];
      out[ro + (2 * w + 1) * 16 + lo] = acc1[r];
    }
    if (nt < 3) {
      float ss = p0[0]*p0[0] + p0[1]*p0[1] + p0[2]*p0[2] + p0[3]*p0[3]
               + p1[0]*p1[0] + p1[1]*p1[1] + p1[2]*p1[2] + p1[3]*p1[3];
      #pragma unroll
      for (int m = 1; m < 32; m <<= 1) ss += __shfl_xor(ss, m);
      float sc = 1.0f / fmaxf(sqrtf(ss), 1e-12f);
      u16x8 qb;
      qb[0] = f2bf(p0[0] * sc); qb[1] = f2bf(p0[1] * sc);
      qb[2] = f2bf(p0[2] * sc); qb[3] = f2bf(p0[3] * sc);
      qb[4] = f2bf(p1[0] * sc); qb[5] = f2bf(p1[1] * sc);
      qb[6] = f2bf(p1[2] * sc); qb[7] = f2bf(p1[3] * sc);
      *(u16x8*)&qn[cur ^ 1][(row * 256 + l32 * 8) ^ ((row & 7) << 3)] = qb;
      cur ^= 1;
    }
  }
}

extern "C" void kernel_launch(void* const* d_in, const int* in_sizes, int n_in,
                              void* d_out, int out_size, void* d_ws, size_t ws_size,
                              hipStream_t stream) {
  const float* q = (const float*)d_in[0];
  const float* k = (const float*)d_in[1];
  const float* v = (const float*)d_in[2];
  float* out = (float*)d_out;

  // ws layout: [ktp 16MB][vtp 16MB][partial splits MB][kvT 1MB]
  size_t panels_bytes = 2ull * 1024 * PANEL * 2;  // 32 MB
  int splits = 32;
  while (splits > 2) {
    size_t need = panels_bytes + ((size_t)splits + 1ull) * 1048576ull;
    if (need <= ws_size) break;
    splits >>= 1;
  }
  u16* ktp = (u16*)d_ws;
  u16* vtp = ktp + (size_t)1024 * PANEL;
  u16* partial = vtp + (size_t)1024 * PANEL;
  u16* kvT = partial + (size_t)splits * 524288ull;

  conv_kernel<<<dim3(1024), dim3(512), 0, stream>>>(k, v, ktp, vtp);
  gemm_kernel<<<dim3(splits, NB), dim3(512), 0, stream>>>(ktp, vtp, partial, MM / splits);
  red_kernel<<<dim3(256), dim3(256), 0, stream>>>(partial, kvT, splits);
  ctx_kernel<<<dim3(64, NB), dim3(512), 0, stream>>>(q, kvT, out);
}

// Round 15
// 69.095 us; speedup vs baseline: 1.1130x; 1.1130x over previous
//
#include <hip/hip_runtime.h>

typedef __attribute__((ext_vector_type(4))) float v4f;
typedef __attribute__((ext_vector_type(8))) short short8;
typedef unsigned short u16;
typedef unsigned int u32;
typedef __attribute__((ext_vector_type(2))) unsigned int u32x2;
typedef __attribute__((ext_vector_type(8))) unsigned short u16x8;

#define CDIM 256
#define NB 8
#define NN 4096
#define MM 4096
#define PANEL 8192  // u16 per 32-row panel (256 c x 32 m)

static __device__ __forceinline__ u16 f2bf(float f) {
  unsigned u = __float_as_uint(f);
  u = (u + 0x7fffu + ((u >> 16) & 1u)) >> 16;  // RNE
  return (u16)u;
}
static __device__ __forceinline__ float bf2f(u16 h) {
  return __uint_as_float(((unsigned)h) << 16);
}
static __device__ __forceinline__ u32 pack2(float a, float b) {
  return (u32)f2bf(a) | ((u32)f2bf(b) << 16);
}

// swizzled index into a [256 c][32 m] u16 panel (proven R9-R14)
static __device__ __forceinline__ int sidx32(int c, int m) {
  return (c * 32 + m) ^ (((c >> 1) & 7) << 3);
}

// 4x4 bf16 transpose among lanes {l, l^16, l^32, l^48} (proven R7-R14).
static __device__ __forceinline__ u32x2 xpose4(u32 A, u32 B, int hi) {
  u32 tA = (u32)__shfl_xor((int)A, 32);
  u32 tB = (u32)__shfl_xor((int)B, 32);
  u32 U = (hi < 2) ? A : tB;
  u32 V = (hi < 2) ? tA : B;
  u32 tU = (u32)__shfl_xor((int)U, 16);
  u32 tV = (u32)__shfl_xor((int)V, 16);
  u32 Up, Vp;
  if ((hi & 1) == 0) {
    Up = (U & 0xffffu) | (tU << 16);
    Vp = (V & 0xffffu) | (tV << 16);
  } else {
    Up = (tU >> 16) | (U & 0xffff0000u);
    Vp = (tV >> 16) | (V & 0xffff0000u);
  }
  return (u32x2){Up, Vp};
}

// ---------------- K0: streaming convert+transpose, DENSE global writes ----------------
// 1024 blocks x 512 thr; block = one 32-row panel. xpose4-scatter into LDS (cheap),
// one barrier, then fully-coalesced u16x8 copy to global (R14's 8B/64B-line global
// scatter @1.78 TB/s was the bottleneck).
__global__ __launch_bounds__(512) void conv_kernel(const float* __restrict__ key,
                                                   const float* __restrict__ value,
                                                   u16* __restrict__ ktp,
                                                   u16* __restrict__ vtp) {
  __shared__ __align__(16) u16 KP[PANEL];
  __shared__ __align__(16) u16 VP[PANEL];
  int t = threadIdx.x;
  int w = t >> 6, lane = t & 63, lo = lane & 15, hi = lane >> 4;
  int m0 = w * 4;
  size_t grow = (size_t)blockIdx.x * 32 + m0 + hi;
  const float* kr = key + grow * CDIM + lo * 4;
  const float* vr = value + grow * CDIM + lo * 4;
  v4f kq[4], vq[4];
  #pragma unroll
  for (int qt = 0; qt < 4; ++qt) {
    kq[qt] = *(const v4f*)(kr + qt * 64);
    vq[qt] = *(const v4f*)(vr + qt * 64);
  }
  float ss = 0.f;
  #pragma unroll
  for (int qt = 0; qt < 4; ++qt)
    ss += kq[qt][0]*kq[qt][0] + kq[qt][1]*kq[qt][1] + kq[qt][2]*kq[qt][2] + kq[qt][3]*kq[qt][3];
  #pragma unroll
  for (int m = 1; m < 16; m <<= 1) ss += __shfl_xor(ss, m);  // row spans 16 lanes (lo)
  float sc_ = 1.0f / fmaxf(sqrtf(ss), 1e-12f);
  #pragma unroll
  for (int qt = 0; qt < 4; ++qt) {
    int c = qt * 64 + lo * 4 + hi;
    int idx = sidx32(c, m0);
    u32x2 ko = xpose4(pack2(kq[qt][0] * sc_, kq[qt][1] * sc_),
                      pack2(kq[qt][2] * sc_, kq[qt][3] * sc_), hi);
    *(u32x2*)&KP[idx] = ko;
    u32x2 vo = xpose4(pack2(vq[qt][0], vq[qt][1]),
                      pack2(vq[qt][2], vq[qt][3]), hi);
    *(u32x2*)&VP[idx] = vo;
  }
  __syncthreads();
  // dense copy: 16 u16/thread/panel, fully coalesced
  size_t pb = (size_t)blockIdx.x * PANEL;
  int soff = t * 16;
  u16x8 a0 = *(const u16x8*)&KP[soff];
  u16x8 a1 = *(const u16x8*)&KP[soff + 8];
  *(u16x8*)&ktp[pb + soff] = a0;
  *(u16x8*)&ktp[pb + soff + 8] = a1;
  u16x8 b0 = *(const u16x8*)&VP[soff];
  u16x8 b1 = *(const u16x8*)&VP[soff + 8];
  *(u16x8*)&vtp[pb + soff] = b0;
  *(u16x8*)&vtp[pb + soff + 8] = b1;
}

// ---------------- K1: partial = v^T @ k-hat, from pre-transposed panels ----------------
// Linear staging (swizzle pre-baked). Epilogue now DENSE via LDS bounce
// (4 passes of 64 d-rows, stride-264 scratch: conflict-free scatter, aligned reads).
__global__ __launch_bounds__(512) void gemm_kernel(const u16* __restrict__ ktp,
                                                   const u16* __restrict__ vtp,
                                                   u16* __restrict__ partial, int KC) {
  __shared__ __align__(16) u16 LDSBUF[4 * PANEL];  // KL0|KL1|VL0|VL1 = 64 KB
  int t = threadIdx.x;
  int b = blockIdx.y, s = blockIdx.x;
  int w = t >> 6, lane = t & 63, lo = lane & 15, hi = lane >> 4;
  size_t p0 = ((size_t)b * MM + (size_t)s * KC) >> 5;  // first panel index

  v4f acc[2][16];
  #pragma unroll
  for (int i = 0; i < 2; i++)
    #pragma unroll
    for (int d = 0; d < 16; d++) acc[i][d] = (v4f){0.f, 0.f, 0.f, 0.f};

  int soff = t * 16;  // 512 thr x 16 u16 = PANEL (full coverage)

  auto MF = [&](const u16* KB, const u16* VB) {
    int acol = hi * 8;
    int r0 = w * 32 + lo, r1 = w * 32 + 16 + lo;
    short8 a0 = *(const short8*)&KB[(r0 * 32 + acol) ^ (((r0 >> 1) & 7) << 3)];
    short8 a1 = *(const short8*)&KB[(r1 * 32 + acol) ^ (((r1 >> 1) & 7) << 3)];
    #pragma unroll
    for (int dt = 0; dt < 16; ++dt) {
      int drow = dt * 16 + lo;
      short8 bb = *(const short8*)&VB[(drow * 32 + acol) ^ (((drow >> 1) & 7) << 3)];
      acc[0][dt] = __builtin_amdgcn_mfma_f32_16x16x32_bf16(bb, a0, acc[0][dt], 0, 0, 0);
      acc[1][dt] = __builtin_amdgcn_mfma_f32_16x16x32_bf16(bb, a1, acc[1][dt], 0, 0, 0);
    }
  };

  int nsc = KC >> 5;
  {
    u16x8 k0 = *(const u16x8*)&ktp[p0 * PANEL + soff];
    u16x8 k1 = *(const u16x8*)&ktp[p0 * PANEL + soff + 8];
    u16x8 v0 = *(const u16x8*)&vtp[p0 * PANEL + soff];
    u16x8 v1 = *(const u16x8*)&vtp[p0 * PANEL + soff + 8];
    *(u16x8*)&LDSBUF[soff] = k0;
    *(u16x8*)&LDSBUF[soff + 8] = k1;
    *(u16x8*)&LDSBUF[2 * PANEL + soff] = v0;
    *(u16x8*)&LDSBUF[2 * PANEL + soff + 8] = v1;
  }
  __syncthreads();
  for (int sc = 0; sc < nsc; ++sc) {
    u16x8 k0N, k1N, v0N, v1N;
    if (sc + 1 < nsc) {  // issue next panel's loads; they fly during MF
      size_t pbn = (p0 + sc + 1) * PANEL + soff;
      k0N = *(const u16x8*)&ktp[pbn];
      k1N = *(const u16x8*)&ktp[pbn + 8];
      v0N = *(const u16x8*)&vtp[pbn];
      v1N = *(const u16x8*)&vtp[pbn + 8];
    }
    int cb = sc & 1;
    MF(&LDSBUF[cb * PANEL], &LDSBUF[(2 + cb) * PANEL]);
    if (sc + 1 < nsc) {
      int nb = (sc + 1) & 1;
      *(u16x8*)&LDSBUF[nb * PANEL + soff] = k0N;
      *(u16x8*)&LDSBUF[nb * PANEL + soff + 8] = k1N;
      *(u16x8*)&LDSBUF[(2 + nb) * PANEL + soff] = v0N;
      *(u16x8*)&LDSBUF[(2 + nb) * PANEL + soff + 8] = v1N;
    }
    __syncthreads();
  }

  // epilogue: DENSE partial [s][b][256 d][256 c] via LDS bounce, 4 passes of 64 d-rows
  size_t base = ((size_t)(s * NB + b)) << 16;
  u16* S = LDSBUF;  // scratch (>= 64*264 u16), free after final barrier above
  #pragma unroll
  for (int p = 0; p < 4; ++p) {
    if (p) __syncthreads();
    #pragma unroll
    for (int i = 0; i < 2; i++) {
      int cc = w * 32 + i * 16 + lo;
      #pragma unroll
      for (int dtl = 0; dtl < 4; ++dtl) {
        int dt = p * 4 + dtl;
        int dl = dtl * 16 + hi * 4;
        #pragma unroll
        for (int r = 0; r < 4; r++)
          S[(dl + r) * 264 + cc] = f2bf(acc[i][dt][r]);
      }
    }
    __syncthreads();
    #pragma unroll
    for (int j = 0; j < 2; ++j) {
      int f = t * 32 + j * 16;           // 512 thr x 32 u16 = 16384 (64 rows x 256)
      int row = f >> 8, col = f & 255;
      u16x8 x0 = *(const u16x8*)&S[row * 264 + col];
      u16x8 x1 = *(const u16x8*)&S[row * 264 + col + 8];
      size_t g = base + (size_t)(p * 64 + row) * 256 + col;
      *(u16x8*)&partial[g] = x0;
      *(u16x8*)&partial[g + 8] = x1;
    }
  }
}

// ---------------- K2: elementwise reduce partials, scale 1/N, write kvT[d][c] bf16 ----------------
__global__ __launch_bounds__(256) void red_kernel(const u16* __restrict__ partial,
                                                  u16* __restrict__ kvT, int splits) {
  int j = blockIdx.x * 256 + threadIdx.x;   // 0..65535
  int b = j >> 13;
  int e0 = (j & 8191) * 8;
  size_t off = ((size_t)b << 16) + e0;
  const float inv = 1.0f / 4096.0f;
  float sum[8] = {0.f, 0.f, 0.f, 0.f, 0.f, 0.f, 0.f, 0.f};
  for (int s = 0; s < splits; ++s) {
    u16x8 p = *(const u16x8*)&partial[(((size_t)s * NB) << 16) + off];
    #pragma unroll
    for (int x = 0; x < 8; ++x) sum[x] += bf2f(p[x]);
  }
  u16x8 o;
  #pragma unroll
  for (int x = 0; x < 8; ++x) o[x] = f2bf(sum[x] * inv);
  *(u16x8*)&kvT[off] = o;
}

// ---------------- K3: out = normalize(q) @ kv (unchanged, proven) ----------------
__global__ __launch_bounds__(512) void ctx_kernel(const float* __restrict__ query,
                                                  const u16* __restrict__ kvT,
                                                  float* __restrict__ out) {
  __shared__ __align__(16) u16 qn[2][16 * 256];
  int t = threadIdx.x;
  int b = blockIdx.y;
  int tile0 = blockIdx.x * 4;
  int w = t >> 6, lane = t & 63, lo = lane & 15, hi = lane >> 4;
  int row = t >> 5, l32 = t & 31;
  const float* qbase = query + (size_t)b * NN * CDIM + (size_t)row * CDIM + l32 * 8;

  const float* qr0 = qbase + (size_t)(tile0 * 16) * CDIM;
  v4f x0 = *(const v4f*)qr0;
  v4f x1 = *(const v4f*)(qr0 + 4);

  const u16* kvb = kvT + ((size_t)b << 16);
  short8 Bf[2][8];
  #pragma unroll
  for (int i = 0; i < 2; i++) {
    int dr = (2 * w + i) * 16 + lo;
    #pragma unroll
    for (int kc = 0; kc < 8; kc++)
      Bf[i][kc] = *(const short8*)&kvb[(size_t)dr * 256 + kc * 32 + 8 * hi];
  }

  {
    float ss = x0[0]*x0[0] + x0[1]*x0[1] + x0[2]*x0[2] + x0[3]*x0[3]
             + x1[0]*x1[0] + x1[1]*x1[1] + x1[2]*x1[2] + x1[3]*x1[3];
    #pragma unroll
    for (int m = 1; m < 32; m <<= 1) ss += __shfl_xor(ss, m);
    float sc = 1.0f / fmaxf(sqrtf(ss), 1e-12f);
    u16x8 qb;
    qb[0] = f2bf(x0[0] * sc); qb[1] = f2bf(x0[1] * sc);
    qb[2] = f2bf(x0[2] * sc); qb[3] = f2bf(x0[3] * sc);
    qb[4] = f2bf(x1[0] * sc); qb[5] = f2bf(x1[1] * sc);
    qb[6] = f2bf(x1[2] * sc); qb[7] = f2bf(x1[3] * sc);
    *(u16x8*)&qn[0][(row * 256 + l32 * 8) ^ ((row & 7) << 3)] = qb;
  }

  int cur = 0;
  #pragma unroll
  for (int nt = 0; nt < 4; ++nt) {
    v4f p0, p1;
    if (nt < 3) {
      const float* qr = qbase + (size_t)((tile0 + nt + 1) * 16) * CDIM;
      p0 = *(const v4f*)qr;
      p1 = *(const v4f*)(qr + 4);
    }
    __syncthreads();
    short8 Af[8];
    #pragma unroll
    for (int kc = 0; kc < 8; kc++)
      Af[kc] = *(const short8*)&qn[cur][(lo * 256 + kc * 32 + 8 * hi) ^ ((lo & 7) << 3)];
    v4f acc0 = (v4f){0.f, 0.f, 0.f, 0.f};
    v4f acc1 = (v4f){0.f, 0.f, 0.f, 0.f};
    #pragma unroll
    for (int kc = 0; kc < 8; kc++) {
      acc0 = __builtin_amdgcn_mfma_f32_16x16x32_bf16(Af[kc], Bf[0][kc], acc0, 0, 0, 0);
      acc1 = __builtin_amdgcn_mfma_f32_16x16x32_bf16(Af[kc], Bf[1][kc], acc1, 0, 0, 0);
    }
    int n0 = (tile0 + nt) * 16;
    #pragma unroll
    for (int r = 0; r < 4; r++) {
      size_t ro = (size_t)(b * NN + n0 + 4 * hi + r) * CDIM;
      out[ro + (2 * w) * 16 + lo] = acc0[r];
      out[ro + (2 * w + 1) * 16 + lo] = acc1[r];
    }
    if (nt < 3) {
      float ss = p0[0]*p0[0] + p0[1]*p0[1] + p0[2]*p0[2] + p0[3]*p0[3]
               + p1[0]*p1[0] + p1[1]*p1[1] + p1[2]*p1[2] + p1[3]*p1[3];
      #pragma unroll
      for (int m = 1; m < 32; m <<= 1) ss += __shfl_xor(ss, m);
      float sc = 1.0f / fmaxf(sqrtf(ss), 1e-12f);
      u16x8 qb;
      qb[0] = f2bf(p0[0] * sc); qb[1] = f2bf(p0[1] * sc);
      qb[2] = f2bf(p0[2] * sc); qb[3] = f2bf(p0[3] * sc);
      qb[4] = f2bf(p1[0] * sc); qb[5] = f2bf(p1[1] * sc);
      qb[6] = f2bf(p1[2] * sc); qb[7] = f2bf(p1[3] * sc);
      *(u16x8*)&qn[cur ^ 1][(row * 256 + l32 * 8) ^ ((row & 7) << 3)] = qb;
      cur ^= 1;
    }
  }
}

extern "C" void kernel_launch(void* const* d_in, const int* in_sizes, int n_in,
                              void* d_out, int out_size, void* d_ws, size_t ws_size,
                              hipStream_t stream) {
  const float* q = (const float*)d_in[0];
  const float* k = (const float*)d_in[1];
  const float* v = (const float*)d_in[2];
  float* out = (float*)d_out;

  // ws layout: [ktp 16MB][vtp 16MB][partial splits MB][kvT 1MB]
  size_t panels_bytes = 2ull * 1024 * PANEL * 2;  // 32 MB
  int splits = 32;
  while (splits > 2) {
    size_t need = panels_bytes + ((size_t)splits + 1ull) * 1048576ull;
    if (need <= ws_size) break;
    splits >>= 1;
  }
  u16* ktp = (u16*)d_ws;
  u16* vtp = ktp + (size_t)1024 * PANEL;
  u16* partial = vtp + (size_t)1024 * PANEL;
  u16* kvT = partial + (size_t)splits * 524288ull;

  conv_kernel<<<dim3(1024), dim3(512), 0, stream>>>(k, v, ktp, vtp);
  gemm_kernel<<<dim3(splits, NB), dim3(512), 0, stream>>>(ktp, vtp, partial, MM / splits);
  red_kernel<<<dim3(256), dim3(256), 0, stream>>>(partial, kvT, splits);
  ctx_kernel<<<dim3(64, NB), dim3(512), 0, stream>>>(q, kvT, out);
}

// Round 16
// 59.772 us; speedup vs baseline: 1.2866x; 1.1560x over previous
//
#include <hip/hip_runtime.h>

typedef __attribute__((ext_vector_type(4))) float v4f;
typedef __attribute__((ext_vector_type(8))) short short8;
typedef unsigned short u16;
typedef unsigned int u32;
typedef __attribute__((ext_vector_type(2))) unsigned int u32x2;
typedef __attribute__((ext_vector_type(8))) unsigned short u16x8;

#define CDIM 256
#define NB 8
#define NN 4096
#define MM 4096
#define PANEL 8192  // u16 per [256 c][32 m] subtile

static __device__ __forceinline__ u16 f2bf(float f) {
  unsigned u = __float_as_uint(f);
  u = (u + 0x7fffu + ((u >> 16) & 1u)) >> 16;  // RNE
  return (u16)u;
}
static __device__ __forceinline__ float bf2f(u16 h) {
  return __uint_as_float(((unsigned)h) << 16);
}
static __device__ __forceinline__ u32 pack2(float a, float b) {
  return (u32)f2bf(a) | ((u32)f2bf(b) << 16);
}

// swizzled index into a [256 c][32 m] u16 tile (proven R9-R15)
static __device__ __forceinline__ int sidx32(int c, int m) {
  return (c * 32 + m) ^ (((c >> 1) & 7) << 3);
}

// 4x4 bf16 transpose among lanes {l, l^16, l^32, l^48} (proven R7-R15).
static __device__ __forceinline__ u32x2 xpose4(u32 A, u32 B, int hi) {
  u32 tA = (u32)__shfl_xor((int)A, 32);
  u32 tB = (u32)__shfl_xor((int)B, 32);
  u32 U = (hi < 2) ? A : tB;
  u32 V = (hi < 2) ? tA : B;
  u32 tU = (u32)__shfl_xor((int)U, 16);
  u32 tV = (u32)__shfl_xor((int)V, 16);
  u32 Up, Vp;
  if ((hi & 1) == 0) {
    Up = (U & 0xffffu) | (tU << 16);
    Vp = (V & 0xffffu) | (tV << 16);
  } else {
    Up = (tU >> 16) | (U & 0xffff0000u);
    Vp = (tV >> 16) | (V & 0xffff0000u);
  }
  return (u32x2){Up, Vp};
}

#define BARRIER() do { \
  asm volatile("s_waitcnt lgkmcnt(0)" ::: "memory"); \
  __builtin_amdgcn_s_barrier(); \
  __builtin_amdgcn_sched_barrier(0); \
} while (0)

#define PIN() __builtin_amdgcn_sched_barrier(0)

// ---------------- K1: kv partials = v^T @ (k/||k||), split-K, output [d][c] ----------------
// R12 monolith (best-known main loop) + DENSE epilogue via LDS bounce (R15-validated):
// R12's epilogue wrote 32B segments @512B stride (WRITE 46MB vs 33.5 ideal).
__global__ __launch_bounds__(512, 1) void kv_kernel(const float* __restrict__ key,
                                                    const float* __restrict__ value,
                                                    u16* __restrict__ partial, int KC) {
  __shared__ __align__(16) u16 LDSBUF[4 * PANEL];  // KL0|KL1|VL0|VL1 = 64 KB
  u16* KL[2] = { LDSBUF, LDSBUF + PANEL };
  u16* VL[2] = { LDSBUF + 2 * PANEL, LDSBUF + 3 * PANEL };
  int t = threadIdx.x;
  int b = blockIdx.y, s = blockIdx.x;
  int w = t >> 6, lane = t & 63, lo = lane & 15, hi = lane >> 4;

  const float* kbase = key + ((size_t)b * MM + (size_t)s * KC) * CDIM;
  const float* vbase = value + ((size_t)b * MM + (size_t)s * KC) * CDIM;

  v4f acc[2][16];
  #pragma unroll
  for (int i = 0; i < 2; i++)
    #pragma unroll
    for (int d = 0; d < 16; d++) acc[i][d] = (v4f){0.f, 0.f, 0.f, 0.f};

  v4f kqA[4], vqA[4], kqB[4], vqB[4];  // two named staging sets (rule #20)

  auto LOADS = [&](int sc, v4f (&kq)[4], v4f (&vq)[4]) {
    int row = sc * 32 + w * 4 + hi;  // wave w stages rows w*4..w*4+3
    const float* kr = kbase + (size_t)row * CDIM + lo * 4;
    const float* vr = vbase + (size_t)row * CDIM + lo * 4;
    #pragma unroll
    for (int qt = 0; qt < 4; ++qt) {
      kq[qt] = *(const v4f*)(kr + qt * 64);
      vq[qt] = *(const v4f*)(vr + qt * 64);
    }
  };
  auto STORE = [&](int bufi, v4f (&kq)[4], v4f (&vq)[4]) {
    int m0 = w * 4;
    float ss = 0.f;
    #pragma unroll
    for (int qt = 0; qt < 4; ++qt)
      ss += kq[qt][0]*kq[qt][0] + kq[qt][1]*kq[qt][1] + kq[qt][2]*kq[qt][2] + kq[qt][3]*kq[qt][3];
    #pragma unroll
    for (int m = 1; m < 16; m <<= 1) ss += __shfl_xor(ss, m);  // row spans 16 lanes
    float sc_ = 1.0f / fmaxf(sqrtf(ss), 1e-12f);
    #pragma unroll
    for (int qt = 0; qt < 4; ++qt) {
      int c = qt * 64 + lo * 4 + hi;
      u32x2 ko = xpose4(pack2(kq[qt][0] * sc_, kq[qt][1] * sc_),
                        pack2(kq[qt][2] * sc_, kq[qt][3] * sc_), hi);
      *(u32x2*)&KL[bufi][sidx32(c, m0)] = ko;
      u32x2 vo = xpose4(pack2(vq[qt][0], vq[qt][1]),
                        pack2(vq[qt][2], vq[qt][3]), hi);
      *(u32x2*)&VL[bufi][sidx32(c, m0)] = vo;
    }
  };
  auto MF = [&](const u16* KB, const u16* VB) {
    int acol = hi * 8;
    int r0 = w * 32 + lo, r1 = w * 32 + 16 + lo;
    short8 a0 = *(const short8*)&KB[(r0 * 32 + acol) ^ (((r0 >> 1) & 7) << 3)];
    short8 a1 = *(const short8*)&KB[(r1 * 32 + acol) ^ (((r1 >> 1) & 7) << 3)];
    #pragma unroll
    for (int dt = 0; dt < 16; ++dt) {
      int drow = dt * 16 + lo;
      short8 bb = *(const short8*)&VB[(drow * 32 + acol) ^ (((drow >> 1) & 7) << 3)];
      acc[0][dt] = __builtin_amdgcn_mfma_f32_16x16x32_bf16(bb, a0, acc[0][dt], 0, 0, 0);
      acc[1][dt] = __builtin_amdgcn_mfma_f32_16x16x32_bf16(bb, a1, acc[1][dt], 0, 0, 0);
    }
  };

  // ---- 2-deep pipeline over 32-row subtiles (nsc = KC/32 >= 4) ----
  int nsc = KC >> 5;
  LOADS(0, kqA, vqA);
  PIN();
  LOADS(1, kqB, vqB);
  PIN();
  STORE(0, kqA, vqA);
  BARRIER();
  for (int i = 0; i < nsc; i += 2) {
    if (i + 2 < nsc) { LOADS(i + 2, kqA, vqA); PIN(); }
    MF(KL[0], VL[0]);
    if (i + 1 < nsc) {
      STORE(1, kqB, vqB);
      BARRIER();
      if (i + 3 < nsc) { LOADS(i + 3, kqB, vqB); PIN(); }
      MF(KL[1], VL[1]);
      if (i + 2 < nsc) {
        STORE(0, kqA, vqA);
        BARRIER();
      }
    }
  }

  // ---- epilogue: DENSE partial [s][b][256 d][256 c] via LDS bounce ----
  // 4 passes of 64 d-rows; stride-264 scratch (bank-aliasing <=4-way, one-time);
  // then fully-coalesced u16x8 stores (fixes the 32B/512B-stride scatter).
  __syncthreads();  // all MF reads of LDSBUF complete before scratch reuse
  size_t base = ((size_t)(s * NB + b)) << 16;
  u16* S = LDSBUF;  // 64x264 = 16896 u16 <= 32768
  #pragma unroll
  for (int p = 0; p < 4; ++p) {
    if (p) __syncthreads();
    #pragma unroll
    for (int i = 0; i < 2; i++) {
      int cc = w * 32 + i * 16 + lo;
      #pragma unroll
      for (int dtl = 0; dtl < 4; ++dtl) {
        int dt = p * 4 + dtl;
        int dl = dtl * 16 + hi * 4;
        #pragma unroll
        for (int r = 0; r < 4; r++)
          S[(dl + r) * 264 + cc] = f2bf(acc[i][dt][r]);
      }
    }
    __syncthreads();
    #pragma unroll
    for (int j = 0; j < 2; ++j) {
      int f = t * 32 + j * 16;           // 512 thr x 32 u16 = 16384 (64 rows x 256)
      int row = f >> 8, col = f & 255;
      u16x8 x0 = *(const u16x8*)&S[row * 264 + col];
      u16x8 x1 = *(const u16x8*)&S[row * 264 + col + 8];
      size_t g = base + (size_t)(p * 64 + row) * 256 + col;
      *(u16x8*)&partial[g] = x0;
      *(u16x8*)&partial[g + 8] = x1;
    }
  }
}

// ---------------- K2: elementwise reduce partials, scale 1/N, write kvT[d][c] bf16 ----------------
__global__ __launch_bounds__(256) void red_kernel(const u16* __restrict__ partial,
                                                  u16* __restrict__ kvT, int splits) {
  int j = blockIdx.x * 256 + threadIdx.x;   // 0..65535
  int b = j >> 13;
  int e0 = (j & 8191) * 8;
  size_t off = ((size_t)b << 16) + e0;
  const float inv = 1.0f / 4096.0f;
  float sum[8] = {0.f, 0.f, 0.f, 0.f, 0.f, 0.f, 0.f, 0.f};
  for (int s = 0; s < splits; ++s) {
    u16x8 p = *(const u16x8*)&partial[(((size_t)s * NB) << 16) + off];
    #pragma unroll
    for (int x = 0; x < 8; ++x) sum[x] += bf2f(p[x]);
  }
  u16x8 o;
  #pragma unroll
  for (int x = 0; x < 8; ++x) o[x] = f2bf(sum[x] * inv);
  *(u16x8*)&kvT[off] = o;
}

// ---------------- K3: out = normalize(q) @ kv (unchanged, proven) ----------------
__global__ __launch_bounds__(512) void ctx_kernel(const float* __restrict__ query,
                                                  const u16* __restrict__ kvT,
                                                  float* __restrict__ out) {
  __shared__ __align__(16) u16 qn[2][16 * 256];
  int t = threadIdx.x;
  int b = blockIdx.y;
  int tile0 = blockIdx.x * 4;
  int w = t >> 6, lane = t & 63, lo = lane & 15, hi = lane >> 4;
  int row = t >> 5, l32 = t & 31;
  const float* qbase = query + (size_t)b * NN * CDIM + (size_t)row * CDIM + l32 * 8;

  const float* qr0 = qbase + (size_t)(tile0 * 16) * CDIM;
  v4f x0 = *(const v4f*)qr0;
  v4f x1 = *(const v4f*)(qr0 + 4);

  const u16* kvb = kvT + ((size_t)b << 16);
  short8 Bf[2][8];
  #pragma unroll
  for (int i = 0; i < 2; i++) {
    int dr = (2 * w + i) * 16 + lo;
    #pragma unroll
    for (int kc = 0; kc < 8; kc++)
      Bf[i][kc] = *(const short8*)&kvb[(size_t)dr * 256 + kc * 32 + 8 * hi];
  }

  {
    float ss = x0[0]*x0[0] + x0[1]*x0[1] + x0[2]*x0[2] + x0[3]*x0[3]
             + x1[0]*x1[0] + x1[1]*x1[1] + x1[2]*x1[2] + x1[3]*x1[3];
    #pragma unroll
    for (int m = 1; m < 32; m <<= 1) ss += __shfl_xor(ss, m);
    float sc = 1.0f / fmaxf(sqrtf(ss), 1e-12f);
    u16x8 qb;
    qb[0] = f2bf(x0[0] * sc); qb[1] = f2bf(x0[1] * sc);
    qb[2] = f2bf(x0[2] * sc); qb[3] = f2bf(x0[3] * sc);
    qb[4] = f2bf(x1[0] * sc); qb[5] = f2bf(x1[1] * sc);
    qb[6] = f2bf(x1[2] * sc); qb[7] = f2bf(x1[3] * sc);
    *(u16x8*)&qn[0][(row * 256 + l32 * 8) ^ ((row & 7) << 3)] = qb;
  }

  int cur = 0;
  #pragma unroll
  for (int nt = 0; nt < 4; ++nt) {
    v4f p0, p1;
    if (nt < 3) {
      const float* qr = qbase + (size_t)((tile0 + nt + 1) * 16) * CDIM;
      p0 = *(const v4f*)qr;
      p1 = *(const v4f*)(qr + 4);
    }
    __syncthreads();
    short8 Af[8];
    #pragma unroll
    for (int kc = 0; kc < 8; kc++)
      Af[kc] = *(const short8*)&qn[cur][(lo * 256 + kc * 32 + 8 * hi) ^ ((lo & 7) << 3)];
    v4f acc0 = (v4f){0.f, 0.f, 0.f, 0.f};
    v4f acc1 = (v4f){0.f, 0.f, 0.f, 0.f};
    #pragma unroll
    for (int kc = 0; kc < 8; kc++) {
      acc0 = __builtin_amdgcn_mfma_f32_16x16x32_bf16(Af[kc], Bf[0][kc], acc0, 0, 0, 0);
      acc1 = __builtin_amdgcn_mfma_f32_16x16x32_bf16(Af[kc], Bf[1][kc], acc1, 0, 0, 0);
    }
    int n0 = (tile0 + nt) * 16;
    #pragma unroll
    for (int r = 0; r < 4; r++) {
      size_t ro = (size_t)(b * NN + n0 + 4 * hi + r) * CDIM;
      out[ro + (2 * w) * 16 + lo] = acc0[r];
      out[ro + (2 * w + 1) * 16 + lo] = acc1[r];
    }
    if (nt < 3) {
      float ss = p0[0]*p0[0] + p0[1]*p0[1] + p0[2]*p0[2] + p0[3]*p0[3]
               + p1[0]*p1[0] + p1[1]*p1[1] + p1[2]*p1[2] + p1[3]*p1[3];
      #pragma unroll
      for (int m = 1; m < 32; m <<= 1) ss += __shfl_xor(ss, m);
      float sc = 1.0f / fmaxf(sqrtf(ss), 1e-12f);
      u16x8 qb;
      qb[0] = f2bf(p0[0] * sc); qb[1] = f2bf(p0[1] * sc);
      qb[2] = f2bf(p0[2] * sc); qb[3] = f2bf(p0[3] * sc);
      qb[4] = f2bf(p1[0] * sc); qb[5] = f2bf(p1[1] * sc);
      qb[6] = f2bf(p1[2] * sc); qb[7] = f2bf(p1[3] * sc);
      *(u16x8*)&qn[cur ^ 1][(row * 256 + l32 * 8) ^ ((row & 7) << 3)] = qb;
      cur ^= 1;
    }
  }
}

extern "C" void kernel_launch(void* const* d_in, const int* in_sizes, int n_in,
                              void* d_out, int out_size, void* d_ws, size_t ws_size,
                              hipStream_t stream) {
  const float* q = (const float*)d_in[0];
  const float* k = (const float*)d_in[1];
  const float* v = (const float*)d_in[2];
  float* out = (float*)d_out;

  // ws layout: [partial: splits*8*256*256 bf16][kvT: 8*256*256 bf16]
  int splits = 32;
  while (splits > 2) {
    size_t need = ((size_t)splits + 1ull) * 1048576ull;
    if (need <= ws_size) break;
    splits >>= 1;
  }
  u16* partial = (u16*)d_ws;
  u16* kvT = (u16*)((char*)d_ws + (size_t)splits * 1048576ull);

  kv_kernel<<<dim3(splits, NB), dim3(512), 0, stream>>>(k, v, partial, MM / splits);
  red_kernel<<<dim3(256), dim3(256), 0, stream>>>(partial, kvT, splits);
  ctx_kernel<<<dim3(64, NB), dim3(512), 0, stream>>>(q, kvT, out);
}